// Round 6
// baseline (449.457 us; speedup 1.0000x reference)
//
#include <hip/hip_runtime.h>
#include <math.h>

#define EPS 1e-5f

typedef __attribute__((ext_vector_type(8))) short short8;
typedef __attribute__((ext_vector_type(4))) float float4v;

__device__ __forceinline__ bool better(float v1, int i1, float v2, int i2) {
  return (v1 > v2) || (v1 == v2 && i1 < i2);
}

__device__ __forceinline__ unsigned short f2bf(float f) {
  unsigned int u = __float_as_uint(f);
  unsigned int r = u + 0x7fffu + ((u >> 16) & 1u);
  return (unsigned short)(r >> 16);
}
__device__ __forceinline__ float bf2f(unsigned short s) {
  return __uint_as_float(((unsigned int)s) << 16);
}

// Row-coefficient table: RCtab[situation][kr][dr]
// situation: 0 = even phase (R=2i), 1 = odd phase (R=2i+1),
//            2 = lo edge (R=0, base row 0), 3 = hi edge (R=255, base row 125)
// Effective 3x3-on-x filter row coefs; derived from half-pixel bilinear + clamp.
__device__ __constant__ float RCtab[4][3][3] = {
  {{0.75f, 0.25f, 0.f}, {0.25f, 0.75f, 0.f}, {0.f, 0.75f, 0.25f}},
  {{0.25f, 0.75f, 0.f}, {0.f, 0.75f, 0.25f}, {0.f, 0.25f, 0.75f}},
  {{0.f, 0.f, 0.f},     {1.0f, 0.f, 0.f},    {0.75f, 0.25f, 0.f}},
  {{0.f, 0.25f, 0.75f}, {0.f, 0.f, 1.0f},    {0.f, 0.f, 0.f}},
};

// ---------------------------------------------------------------------------
// K0: precompute (a) 4 interior phase filters as bf16 hi/lo for MFMA B-frags,
//     (b) 16 (row-sit x col-sit) fp32 filter sets for the border fixup.
// ---------------------------------------------------------------------------
__global__ __launch_bounds__(256) void k_wprep(const float* __restrict__ w1,
                                               unsigned short* __restrict__ Wphase,
                                               float* __restrict__ EdgeEff) {
  int e = blockIdx.x * 256 + threadIdx.x;
  if (e < 147456) {
    // interior phase filters, bf16 hi/lo, B-frag layout
    int cil = e & 31, co = (e >> 5) & 63, ck = (e >> 11) & 1;
    int tap = (e >> 12) % 9, ph = e / 36864;     // ph = pr*2+pc
    int pr = ph >> 1, pc = ph & 1;
    int dr = tap / 3, dc = tap % 3;
    int ci = ck * 32 + cil;
    const float* wp = w1 + (co * 64 + ci) * 9;
    float eff = 0.f;
    #pragma unroll
    for (int kr = 0; kr < 3; ++kr)
      #pragma unroll
      for (int kc = 0; kc < 3; ++kc)
        eff += wp[kr * 3 + kc] * RCtab[pr][kr][dr] * RCtab[pc][kc][dc];
    unsigned short hi = f2bf(eff);
    unsigned short lo = f2bf(eff - bf2f(hi));
    int g = (ph * 9 + tap) * 2 + ck;
    Wphase[g * 4096 + co * 32 + cil] = hi;
    Wphase[g * 4096 + 2048 + co * 32 + cil] = lo;
  } else if (e < 147456 + 589824) {
    int e2 = e - 147456;
    int co = e2 & 63, tap = (e2 >> 6) % 9, ci = (e2 / 576) & 63, set = e2 / 36864;
    int rs = set >> 2, cs = set & 3;
    int dr = tap / 3, dc = tap % 3;
    const float* wp = w1 + (co * 64 + ci) * 9;
    float eff = 0.f;
    #pragma unroll
    for (int kr = 0; kr < 3; ++kr)
      #pragma unroll
      for (int kc = 0; kc < 3; ++kc)
        eff += wp[kr * 3 + kc] * RCtab[rs][kr][dr] * RCtab[cs][kc][dc];
    EdgeEff[set * 36864 + (ci * 9 + tap) * 64 + co] = eff;
  }
}

// ---------------------------------------------------------------------------
// K1: conv(upsample) via 4 phase filters on x directly. Block = 16x16 up-tile
// x 2 batches; wave = phase; 1 barrier before an 18-iter barrier-free MFMA
// loop (bf16 hi/lo 3-pass). Epilogue: BN1+ReLU -> LDS V -> fp32 1x1 + BN2 +
// reserve filter. Border lines are wrong here; k_fix overwrites them.
// ---------------------------------------------------------------------------
__global__ __launch_bounds__(256, 2) void k_front(
    const float* __restrict__ x, const unsigned short* __restrict__ Wphase,
    const float* __restrict__ b1, const float* __restrict__ g1,
    const float* __restrict__ be1, const float* __restrict__ m1,
    const float* __restrict__ v1, const float* __restrict__ w2,
    const float* __restrict__ g2, const float* __restrict__ be2,
    const float* __restrict__ m2, const float* __restrict__ v2,
    float* __restrict__ xf)
{
  // 8 staging buffers [b][ck][hl] of 100 pos x 40 shorts = 64000 B,
  // aliased by epilogue V fp32 256x65 = 66560 B.
  __shared__ __align__(16) char lds[66560];
  unsigned short* XS = (unsigned short*)lds;
  float* V = (float*)lds;
  __shared__ float w2s[512];
  __shared__ float A1s[64], C1s[64];
  __shared__ float s2s[8], sh2s[8];

  const int tid = threadIdx.x;
  const int bx = blockIdx.x, by = blockIdx.y, bz = blockIdx.z;

  for (int i = tid; i < 512; i += 256) w2s[i] = w2[i];
  if (tid < 64) {
    float sc = g1[tid] * rsqrtf(v1[tid] + EPS);
    A1s[tid] = sc;
    C1s[tid] = sc * (b1[tid] - m1[tid]) + be1[tid];
  }
  if (tid < 8) {
    float sc = g2[tid] * rsqrtf(v2[tid] + EPS);
    s2s[tid] = sc;
    sh2s[tid] = be2[tid] - m2[tid] * sc;
  }

  // --- stage clamped 10x10 x-tile, 64 ci, hi/lo, both batches ---
  if (tid < 200) {
    int ckh = tid / 100;
    int pos = tid % 100;
    int r = pos / 10, c = pos % 10;
    int rr = min(max(by * 8 - 1 + r, 0), 127);
    int cc = min(max(bx * 8 - 1 + c, 0), 127);
    #pragma unroll
    for (int b = 0; b < 2; ++b) {
      const float* xp = x + (size_t)((bz * 2 + b) * 64 + ckh * 32) * 16384 + rr * 128 + cc;
      unsigned int* dh = (unsigned int*)(XS + ((b * 2 + ckh) * 2 + 0) * 4000) + pos * 20;
      unsigned int* dl = (unsigned int*)(XS + ((b * 2 + ckh) * 2 + 1) * 4000) + pos * 20;
      for (int cp = 0; cp < 16; ++cp) {
        float v0 = xp[(size_t)(2 * cp) * 16384];
        float v1x = xp[(size_t)(2 * cp + 1) * 16384];
        unsigned short h0 = f2bf(v0), h1 = f2bf(v1x);
        unsigned short l0 = f2bf(v0 - bf2f(h0)), l1 = f2bf(v1x - bf2f(h1));
        dh[cp] = (unsigned int)h0 | ((unsigned int)h1 << 16);
        dl[cp] = (unsigned int)l0 | ((unsigned int)l1 << 16);
      }
    }
  }
  __syncthreads();

  const int l = tid & 63, wv = tid >> 6;     // wv = phase = pr*2+pc
  const int pr = wv >> 1, pc = wv & 1;
  const int lm = l & 15, q = l >> 4;
  const int arow = lm >> 3, acol = lm & 7;

  float4v acc[2][4][4];
  #pragma unroll
  for (int b = 0; b < 2; ++b)
    #pragma unroll
    for (int mt = 0; mt < 4; ++mt)
      #pragma unroll
      for (int nt = 0; nt < 4; ++nt) acc[b][mt][nt] = (float4v){0.f, 0.f, 0.f, 0.f};

  #pragma unroll
  for (int ck = 0; ck < 2; ++ck) {
    #pragma unroll
    for (int tap = 0; tap < 9; ++tap) {
      const int dr = tap / 3, dc = tap % 3;
      const unsigned short* wb = Wphase + ((wv * 9 + tap) * 2 + ck) * 4096;
      short8 bh[4], bl[4];
      #pragma unroll
      for (int nt = 0; nt < 4; ++nt) {
        int off = (nt * 16 + lm) * 32 + q * 8;
        bh[nt] = *(const short8*)(wb + off);
        bl[nt] = *(const short8*)(wb + 2048 + off);
      }
      #pragma unroll
      for (int b = 0; b < 2; ++b) {
        const unsigned short* XH = XS + ((b * 2 + ck) * 2 + 0) * 4000;
        const unsigned short* XL = XS + ((b * 2 + ck) * 2 + 1) * 4000;
        #pragma unroll
        for (int mt = 0; mt < 4; ++mt) {
          int pos = (mt * 2 + arow + dr) * 10 + acol + dc;
          short8 ah = *(const short8*)(XH + pos * 40 + q * 8);
          short8 al = *(const short8*)(XL + pos * 40 + q * 8);
          #pragma unroll
          for (int nt = 0; nt < 4; ++nt) {
            acc[b][mt][nt] = __builtin_amdgcn_mfma_f32_16x16x32_bf16(ah, bh[nt], acc[b][mt][nt], 0, 0, 0);
            acc[b][mt][nt] = __builtin_amdgcn_mfma_f32_16x16x32_bf16(al, bh[nt], acc[b][mt][nt], 0, 0, 0);
            acc[b][mt][nt] = __builtin_amdgcn_mfma_f32_16x16x32_bf16(ah, bl[nt], acc[b][mt][nt], 0, 0, 0);
          }
        }
      }
    }
  }

  // --- epilogue per batch: acc -> V (BN1+ReLU) -> fp32 1x1 + BN2 + filter ---
  #pragma unroll
  for (int b = 0; b < 2; ++b) {
    __syncthreads();   // staging (b=0) or previous V reads (b=1) complete
    #pragma unroll
    for (int mt = 0; mt < 4; ++mt) {
      #pragma unroll
      for (int nt = 0; nt < 4; ++nt) {
        int co = nt * 16 + lm;
        float A = A1s[co], Cc = C1s[co];
        #pragma unroll
        for (int r = 0; r < 4; ++r) {
          int p = mt * 16 + q * 4 + r;               // pixel within phase (8x8)
          int ur = 2 * (p >> 3) + pr, uc = 2 * (p & 7) + pc;
          V[(ur * 16 + uc) * 65 + co] = fmaxf(fmaf(A, acc[b][mt][nt][r], Cc), 0.f);
        }
      }
    }
    __syncthreads();
    {
      float a2[8];
      #pragma unroll
      for (int c2 = 0; c2 < 8; ++c2) a2[c2] = 0.f;
      const float* vp = &V[tid * 65];
      for (int co = 0; co < 64; ++co) {
        float xv = vp[co];
        #pragma unroll
        for (int c2 = 0; c2 < 8; ++c2) a2[c2] = fmaf(w2s[c2 * 64 + co], xv, a2[c2]);
      }
      int ur = tid >> 4, uc = tid & 15;
      int batch = bz * 2 + b;
      #pragma unroll
      for (int c2 = 0; c2 < 8; ++c2) {
        float y = fmaf(s2s[c2], a2[c2], sh2s[c2]);
        float o = (y > 1.0f) ? y : 0.f;
        xf[((batch * 8 + c2) * 256 + by * 16 + ur) * 256 + bx * 16 + uc] = o;
      }
    }
  }
}

// ---------------------------------------------------------------------------
// K2: exact fixup of the 4 global border lines (R/C in {0,255}) using the
// 12 boundary filter sets. Grid (seg16, line4, bz8); wave=4px, lane=co.
// ---------------------------------------------------------------------------
__global__ __launch_bounds__(256) void k_fix(
    const float* __restrict__ x, const float* __restrict__ EdgeEff,
    const float* __restrict__ b1, const float* __restrict__ g1,
    const float* __restrict__ be1, const float* __restrict__ m1,
    const float* __restrict__ v1, const float* __restrict__ w2,
    const float* __restrict__ g2, const float* __restrict__ be2,
    const float* __restrict__ m2, const float* __restrict__ v2,
    float* __restrict__ xf)
{
  __shared__ float w2s[512];
  __shared__ float A1s[64], C1s[64];
  __shared__ float s2s[8], sh2s[8];
  const int tid = threadIdx.x;
  for (int i = tid; i < 512; i += 256) w2s[i] = w2[i];
  if (tid < 64) {
    float sc = g1[tid] * rsqrtf(v1[tid] + EPS);
    A1s[tid] = sc;
    C1s[tid] = sc * (b1[tid] - m1[tid]) + be1[tid];
  }
  if (tid < 8) {
    float sc = g2[tid] * rsqrtf(v2[tid] + EPS);
    s2s[tid] = sc;
    sh2s[tid] = be2[tid] - m2[tid] * sc;
  }
  __syncthreads();

  const int w = tid >> 6, co = tid & 63;
  const int seg = blockIdx.x, line = blockIdx.y, bz = blockIdx.z;

  int Rk[4], Ck[4], setk[4], validk[4], offs[4][9];
  #pragma unroll
  for (int k = 0; k < 4; ++k) {
    int u = seg * 16 + w * 4 + k;
    int R, C, rs, cs, rbase, cbase, val = 1;
    if (line == 0)      { R = 0;   C = u; rs = 2; rbase = 0; }
    else if (line == 1) { R = 255; C = u; rs = 3; rbase = 125; }
    else                { C = (line == 2) ? 0 : 255; R = 1 + u; val = (u < 254);
                          rs = R & 1; rbase = (R >> 1) - 1; }
    if (line < 2) { cs = (C == 0) ? 2 : ((C == 255) ? 3 : (C & 1));
                    cbase = (cs == 2) ? 0 : ((cs == 3) ? 125 : (C >> 1) - 1); }
    else          { cs = (line == 2) ? 2 : 3; cbase = (line == 2) ? 0 : 125; }
    Rk[k] = R; Ck[k] = C; setk[k] = (rs << 2) | cs; validk[k] = val;
    #pragma unroll
    for (int tap = 0; tap < 9; ++tap) {
      int rr = min(max(rbase + tap / 3, 0), 127);
      int cc = min(max(cbase + tap % 3, 0), 127);
      offs[k][tap] = rr * 128 + cc;
    }
  }

  float acc[4] = {0.f, 0.f, 0.f, 0.f};
  for (int ci = 0; ci < 64; ++ci) {
    const float* xp = x + (size_t)(bz * 64 + ci) * 16384;
    #pragma unroll
    for (int k = 0; k < 4; ++k) {
      const float* ep = EdgeEff + setk[k] * 36864 + ci * 576 + co;
      #pragma unroll
      for (int tap = 0; tap < 9; ++tap)
        acc[k] = fmaf(ep[tap * 64], xp[offs[k][tap]], acc[k]);
    }
  }

  #pragma unroll
  for (int k = 0; k < 4; ++k) {
    float v = fmaxf(fmaf(A1s[co], acc[k], C1s[co]), 0.f);
    float part[8];
    #pragma unroll
    for (int c2 = 0; c2 < 8; ++c2) part[c2] = w2s[c2 * 64 + co] * v;
    #pragma unroll
    for (int m = 1; m < 64; m <<= 1) {
      #pragma unroll
      for (int c2 = 0; c2 < 8; ++c2) part[c2] += __shfl_xor(part[c2], m, 64);
    }
    if (co < 8 && validk[k]) {
      float y = fmaf(s2s[co], part[co], sh2s[co]);
      float o = (y > 1.0f) ? y : 0.f;
      xf[((bz * 8 + co) * 256 + Rk[k]) * 256 + Ck[k]] = o;
    }
  }
}

// ---------------------------------------------------------------------------
// K3: fused separable 5x5 window-sum + row-max; 16-row chunks.
// ---------------------------------------------------------------------------
__global__ __launch_bounds__(256) void k_sep(const float* __restrict__ xf,
                                             float* __restrict__ ws,
                                             float* __restrict__ rm) {
  __shared__ float bufx[20 * 256];
  __shared__ float bufr[20 * 256];
  const int plane = blockIdx.x >> 4;
  const int r0 = (blockIdx.x & 15) * 16;
  const int t = threadIdx.x;
  const float* xp = xf + plane * 65536;

  for (int i = t; i < 20 * 256; i += 256) {
    int rr = r0 - 2 + (i >> 8);
    bufx[i] = ((unsigned)rr < 256u) ? xp[(rr << 8) | (i & 255)] : 0.f;
  }
  __syncthreads();

  #pragma unroll 4
  for (int i = 0; i < 20; ++i) {
    const float* row = bufx + i * 256;
    float s = 0.f;
    #pragma unroll
    for (int d = -2; d <= 2; ++d) {
      int cc = t + d;
      if ((unsigned)cc < 256u) s += row[cc];
    }
    bufr[i * 256 + t] = s;
  }
  __syncthreads();

  #pragma unroll 4
  for (int i = 0; i < 16; ++i) {
    int j = i + 2;
    float s = bufr[(j - 2) * 256 + t] + bufr[(j - 1) * 256 + t] + bufr[j * 256 + t] +
              bufr[(j + 1) * 256 + t] + bufr[(j + 2) * 256 + t];
    bufx[j * 256 + t] = s;
    ws[plane * 65536 + (r0 + i) * 256 + t] = s;
  }
  __syncthreads();

  #pragma unroll 4
  for (int i = 0; i < 16; ++i) {
    int j = i + 2;
    float m = -HUGE_VALF;
    #pragma unroll
    for (int d = -2; d <= 2; ++d) {
      int cc = t + d;
      if ((unsigned)cc < 256u) m = fmaxf(m, bufx[j * 256 + cc]);
    }
    rm[plane * 65536 + (r0 + i) * 256 + t] = m;
  }
}

// ---------------------------------------------------------------------------
// K4: per-(plane, 32-row chunk) NMS mask + stable top-8 candidates.
// ---------------------------------------------------------------------------
__global__ __launch_bounds__(256) void k_cand(const float* __restrict__ ws,
                                              const float* __restrict__ rm,
                                              float* __restrict__ candv,
                                              int* __restrict__ candi) {
  __shared__ float cv[256 * 8];
  __shared__ int cidx[256 * 8];
  const int t = threadIdx.x;
  const int plane = blockIdx.x >> 3;
  const int r0 = (blockIdx.x & 7) * 32;
  const float* wsp = ws + plane * 65536;
  const float* rmp = rm + plane * 65536;

  float bv[8]; int bi[8];
  #pragma unroll
  for (int k = 0; k < 8; ++k) { bv[k] = -HUGE_VALF; bi[k] = 0x7fffffff; }

  float w0 = (r0 >= 2) ? rmp[(r0 - 2) * 256 + t] : -HUGE_VALF;
  float w1v = (r0 >= 1) ? rmp[(r0 - 1) * 256 + t] : -HUGE_VALF;
  float w2v = rmp[r0 * 256 + t];
  float w3v = rmp[(r0 + 1) * 256 + t];
  for (int r = r0; r < r0 + 32; ++r) {
    float w4v = (r + 2 < 256) ? rmp[(r + 2) * 256 + t] : -HUGE_VALF;
    float mp = fmaxf(fmaxf(fmaxf(w0, w1v), fmaxf(w2v, w3v)), w4v);
    float wsv = wsp[r * 256 + t];
    float mv = (wsv == mp) ? wsv : 0.f;
    int e = (r << 8) | t;
    if (better(mv, e, bv[7], bi[7])) {
      bv[7] = mv; bi[7] = e;
      #pragma unroll
      for (int k = 7; k > 0; --k) {
        if (better(bv[k], bi[k], bv[k - 1], bi[k - 1])) {
          float tv = bv[k]; bv[k] = bv[k - 1]; bv[k - 1] = tv;
          int ti = bi[k]; bi[k] = bi[k - 1]; bi[k - 1] = ti;
        }
      }
    }
    w0 = w1v; w1v = w2v; w2v = w3v; w3v = w4v;
  }

  #pragma unroll
  for (int k = 0; k < 8; ++k) { cv[t * 8 + k] = bv[k]; cidx[t * 8 + k] = bi[k]; }
  __syncthreads();

  for (int s = 128; s >= 1; s >>= 1) {
    if (t < s) {
      float ov[8]; int oi[8];
      int ia = 0, ib = 0;
      #pragma unroll
      for (int k = 0; k < 8; ++k) {
        float va = cv[t * 8 + ia];       int xa = cidx[t * 8 + ia];
        float vb = cv[(t + s) * 8 + ib]; int xb = cidx[(t + s) * 8 + ib];
        if (better(va, xa, vb, xb)) { ov[k] = va; oi[k] = xa; ++ia; }
        else                        { ov[k] = vb; oi[k] = xb; ++ib; }
      }
      #pragma unroll
      for (int k = 0; k < 8; ++k) { cv[t * 8 + k] = ov[k]; cidx[t * 8 + k] = oi[k]; }
    }
    __syncthreads();
  }

  if (t < 8) {
    candv[blockIdx.x * 8 + t] = cv[t];
    candi[blockIdx.x * 8 + t] = cidx[t];
  }
}

// ---------------------------------------------------------------------------
// K5: merge 8x8 candidates per plane (rank by total order), extract patches
// and positions.
// ---------------------------------------------------------------------------
__global__ __launch_bounds__(256) void k_final(const float* __restrict__ candv,
                                               const int* __restrict__ candi,
                                               const float* __restrict__ xf,
                                               float* __restrict__ patches,
                                               float* __restrict__ pos) {
  __shared__ float cvs[64];
  __shared__ int cis[64];
  __shared__ int fidx[8];
  const int t = threadIdx.x;
  const int plane = blockIdx.x;

  if (t < 64) { cvs[t] = candv[plane * 64 + t]; cis[t] = candi[plane * 64 + t]; }
  __syncthreads();
  if (t < 64) {
    float v = cvs[t]; int i = cis[t];
    int rank = 0;
    for (int m = 0; m < 64; ++m)
      if (better(cvs[m], cis[m], v, i)) ++rank;
    if (rank < 8) fidx[rank] = i;
  }
  __syncthreads();

  const float* xfp = xf + plane * 65536;
  if (t < 200) {
    int n = t / 25, e = t % 25;
    int kr = e / 5, kc = e % 5;
    int idx = fidx[n];
    int h = idx >> 8, w = idx & 255;
    int rr = h - 2 + kr, cc = w - 2 + kc;
    float v = ((unsigned)rr < 256u && (unsigned)cc < 256u) ? xfp[rr * 256 + cc] : 0.f;
    patches[plane * 200 + t] = v;
  } else if (t < 232) {
    int qq = t - 200;
    int n = qq >> 2, k = qq & 3;
    int idx = fidx[n];
    int h = idx >> 8, w = idx & 255;
    int val;
    if (k == 0)      val = min(max(w - 2, 0), 255);
    else if (k == 1) val = min(max(h - 2, 0), 255);
    else if (k == 2) val = min(max(w + 2, 0), 255);
    else             val = min(max(h + 2, 0), 255);
    pos[plane * 32 + qq] = (float)val;
  }
}

// ---------------------------------------------------------------------------
extern "C" void kernel_launch(void* const* d_in, const int* in_sizes, int n_in,
                              void* d_out, int out_size, void* d_ws, size_t ws_size,
                              hipStream_t stream) {
  (void)in_sizes; (void)n_in; (void)out_size; (void)ws_size;
  const float* x   = (const float*)d_in[0];
  const float* w1  = (const float*)d_in[1];
  const float* b1  = (const float*)d_in[2];
  const float* g1  = (const float*)d_in[3];
  const float* be1 = (const float*)d_in[4];
  const float* m1  = (const float*)d_in[5];
  const float* v1  = (const float*)d_in[6];
  const float* w2  = (const float*)d_in[7];
  const float* g2  = (const float*)d_in[8];
  const float* be2 = (const float*)d_in[9];
  const float* m2  = (const float*)d_in[10];
  const float* v2  = (const float*)d_in[11];

  float* out = (float*)d_out;
  const int PLANE = 8 * 8 * 256 * 256;   // 4,194,304
  float* xf   = (float*)d_ws;
  float* bufA = xf + PLANE;              // rm; prep tables live here pre-k_sep
  float* bufB = bufA + PLANE;            // window sums
  float* candv = bufB + PLANE;           // 4096 floats
  int*   candi = (int*)(candv + 4096);   // 4096 ints
  unsigned short* Wphase = (unsigned short*)bufA;   // 576 KB
  float* EdgeEff = bufA + 147456;                   // 2.25 MB

  k_wprep<<<2880, 256, 0, stream>>>(w1, Wphase, EdgeEff);
  k_front<<<dim3(16, 16, 4), 256, 0, stream>>>(x, Wphase, b1, g1, be1, m1, v1,
                                               w2, g2, be2, m2, v2, xf);
  k_fix<<<dim3(16, 4, 8), 256, 0, stream>>>(x, EdgeEff, b1, g1, be1, m1, v1,
                                            w2, g2, be2, m2, v2, xf);
  k_sep<<<1024, 256, 0, stream>>>(xf, bufB, bufA);
  k_cand<<<512, 256, 0, stream>>>(bufB, bufA, candv, candi);
  k_final<<<64, 256, 0, stream>>>(candv, candi, xf, out, out + 12800);
}

// Round 7
// 428.212 us; speedup vs baseline: 1.0496x; 1.0496x over previous
//
#include <hip/hip_runtime.h>
#include <math.h>

#define EPS 1e-5f

typedef __attribute__((ext_vector_type(8))) short short8;
typedef __attribute__((ext_vector_type(4))) float float4v;

__device__ __forceinline__ bool better(float v1, int i1, float v2, int i2) {
  return (v1 > v2) || (v1 == v2 && i1 < i2);
}

__device__ __forceinline__ unsigned short f2bf(float f) {
  unsigned int u = __float_as_uint(f);
  unsigned int r = u + 0x7fffu + ((u >> 16) & 1u);
  return (unsigned short)(r >> 16);
}
__device__ __forceinline__ float bf2f(unsigned short s) {
  return __uint_as_float(((unsigned int)s) << 16);
}

// Row-coefficient table: RCtab[situation][kr][dr]
// situation: 0 = even phase (R=2i), 1 = odd phase (R=2i+1),
//            2 = lo edge (R=0, base row 0), 3 = hi edge (R=255, base row 125)
// Effective 3x3-on-x filter row coefs; derived from half-pixel bilinear + clamp.
__device__ __constant__ float RCtab[4][3][3] = {
  {{0.75f, 0.25f, 0.f}, {0.25f, 0.75f, 0.f}, {0.f, 0.75f, 0.25f}},
  {{0.25f, 0.75f, 0.f}, {0.f, 0.75f, 0.25f}, {0.f, 0.25f, 0.75f}},
  {{0.f, 0.f, 0.f},     {1.0f, 0.f, 0.f},    {0.75f, 0.25f, 0.f}},
  {{0.f, 0.25f, 0.75f}, {0.f, 0.f, 1.0f},    {0.f, 0.f, 0.f}},
};

// ---------------------------------------------------------------------------
// K0: precompute (a) 4 interior phase filters as bf16 hi/lo for MFMA B-frags,
//     (b) 16 (row-sit x col-sit) fp32 filter sets for the border fixup.
// ---------------------------------------------------------------------------
__global__ __launch_bounds__(256) void k_wprep(const float* __restrict__ w1,
                                               unsigned short* __restrict__ Wphase,
                                               float* __restrict__ EdgeEff) {
  int e = blockIdx.x * 256 + threadIdx.x;
  if (e < 147456) {
    // interior phase filters, bf16 hi/lo, B-frag layout
    int cil = e & 31, co = (e >> 5) & 63, ck = (e >> 11) & 1;
    int tap = (e >> 12) % 9, ph = e / 36864;     // ph = pr*2+pc
    int pr = ph >> 1, pc = ph & 1;
    int dr = tap / 3, dc = tap % 3;
    int ci = ck * 32 + cil;
    const float* wp = w1 + (co * 64 + ci) * 9;
    float eff = 0.f;
    #pragma unroll
    for (int kr = 0; kr < 3; ++kr)
      #pragma unroll
      for (int kc = 0; kc < 3; ++kc)
        eff += wp[kr * 3 + kc] * RCtab[pr][kr][dr] * RCtab[pc][kc][dc];
    unsigned short hi = f2bf(eff);
    unsigned short lo = f2bf(eff - bf2f(hi));
    int g = (ph * 9 + tap) * 2 + ck;
    Wphase[g * 4096 + co * 32 + cil] = hi;
    Wphase[g * 4096 + 2048 + co * 32 + cil] = lo;
  } else if (e < 147456 + 589824) {
    int e2 = e - 147456;
    int co = e2 & 63, tap = (e2 >> 6) % 9, ci = (e2 / 576) & 63, set = e2 / 36864;
    int rs = set >> 2, cs = set & 3;
    int dr = tap / 3, dc = tap % 3;
    const float* wp = w1 + (co * 64 + ci) * 9;
    float eff = 0.f;
    #pragma unroll
    for (int kr = 0; kr < 3; ++kr)
      #pragma unroll
      for (int kc = 0; kc < 3; ++kc)
        eff += wp[kr * 3 + kc] * RCtab[rs][kr][dr] * RCtab[cs][kc][dc];
    EdgeEff[set * 36864 + (ci * 9 + tap) * 64 + co] = eff;
  }
}

// ---------------------------------------------------------------------------
// K1: conv(upsample) via 4 phase filters on x directly. Block = 16x16 up-tile
// x 2 batches; wave = phase; 1 barrier before an 18-iter barrier-free MFMA
// loop (bf16 hi/lo 3-pass). Epilogue: BN1+ReLU -> LDS V -> fp32 1x1 + BN2 +
// reserve filter. Border lines are wrong here; k_fix overwrites them.
// launch_bounds (256,1): allow ~512 VGPRs so acc[2][4][4] does NOT spill
// (at (256,2) the allocator capped at 128 VGPRs -> ~246 MB scratch traffic).
// ---------------------------------------------------------------------------
__global__ __launch_bounds__(256, 1) void k_front(
    const float* __restrict__ x, const unsigned short* __restrict__ Wphase,
    const float* __restrict__ b1, const float* __restrict__ g1,
    const float* __restrict__ be1, const float* __restrict__ m1,
    const float* __restrict__ v1, const float* __restrict__ w2,
    const float* __restrict__ g2, const float* __restrict__ be2,
    const float* __restrict__ m2, const float* __restrict__ v2,
    float* __restrict__ xf)
{
  // 8 staging buffers [b][ck][hl] of 100 pos x 40 shorts = 64000 B,
  // aliased by epilogue V fp32 256x65 = 66560 B.
  __shared__ __align__(16) char lds[66560];
  unsigned short* XS = (unsigned short*)lds;
  float* V = (float*)lds;
  __shared__ float w2s[512];
  __shared__ float A1s[64], C1s[64];
  __shared__ float s2s[8], sh2s[8];

  const int tid = threadIdx.x;
  const int bx = blockIdx.x, by = blockIdx.y, bz = blockIdx.z;

  for (int i = tid; i < 512; i += 256) w2s[i] = w2[i];
  if (tid < 64) {
    float sc = g1[tid] * rsqrtf(v1[tid] + EPS);
    A1s[tid] = sc;
    C1s[tid] = sc * (b1[tid] - m1[tid]) + be1[tid];
  }
  if (tid < 8) {
    float sc = g2[tid] * rsqrtf(v2[tid] + EPS);
    s2s[tid] = sc;
    sh2s[tid] = be2[tid] - m2[tid] * sc;
  }

  // --- stage clamped 10x10 x-tile, 64 ci, hi/lo, both batches ---
  if (tid < 200) {
    int ckh = tid / 100;
    int pos = tid % 100;
    int r = pos / 10, c = pos % 10;
    int rr = min(max(by * 8 - 1 + r, 0), 127);
    int cc = min(max(bx * 8 - 1 + c, 0), 127);
    #pragma unroll
    for (int b = 0; b < 2; ++b) {
      const float* xp = x + (size_t)((bz * 2 + b) * 64 + ckh * 32) * 16384 + rr * 128 + cc;
      unsigned int* dh = (unsigned int*)(XS + ((b * 2 + ckh) * 2 + 0) * 4000) + pos * 20;
      unsigned int* dl = (unsigned int*)(XS + ((b * 2 + ckh) * 2 + 1) * 4000) + pos * 20;
      for (int cp = 0; cp < 16; ++cp) {
        float v0 = xp[(size_t)(2 * cp) * 16384];
        float v1x = xp[(size_t)(2 * cp + 1) * 16384];
        unsigned short h0 = f2bf(v0), h1 = f2bf(v1x);
        unsigned short l0 = f2bf(v0 - bf2f(h0)), l1 = f2bf(v1x - bf2f(h1));
        dh[cp] = (unsigned int)h0 | ((unsigned int)h1 << 16);
        dl[cp] = (unsigned int)l0 | ((unsigned int)l1 << 16);
      }
    }
  }
  __syncthreads();

  const int l = tid & 63, wv = tid >> 6;     // wv = phase = pr*2+pc
  const int pr = wv >> 1, pc = wv & 1;
  const int lm = l & 15, q = l >> 4;
  const int arow = lm >> 3, acol = lm & 7;

  float4v acc[2][4][4];
  #pragma unroll
  for (int b = 0; b < 2; ++b)
    #pragma unroll
    for (int mt = 0; mt < 4; ++mt)
      #pragma unroll
      for (int nt = 0; nt < 4; ++nt) acc[b][mt][nt] = (float4v){0.f, 0.f, 0.f, 0.f};

  #pragma unroll
  for (int ck = 0; ck < 2; ++ck) {
    #pragma unroll
    for (int tap = 0; tap < 9; ++tap) {
      const int dr = tap / 3, dc = tap % 3;
      const unsigned short* wb = Wphase + ((wv * 9 + tap) * 2 + ck) * 4096;
      short8 bh[4], bl[4];
      #pragma unroll
      for (int nt = 0; nt < 4; ++nt) {
        int off = (nt * 16 + lm) * 32 + q * 8;
        bh[nt] = *(const short8*)(wb + off);
        bl[nt] = *(const short8*)(wb + 2048 + off);
      }
      #pragma unroll
      for (int b = 0; b < 2; ++b) {
        const unsigned short* XH = XS + ((b * 2 + ck) * 2 + 0) * 4000;
        const unsigned short* XL = XS + ((b * 2 + ck) * 2 + 1) * 4000;
        #pragma unroll
        for (int mt = 0; mt < 4; ++mt) {
          int pos = (mt * 2 + arow + dr) * 10 + acol + dc;
          short8 ah = *(const short8*)(XH + pos * 40 + q * 8);
          short8 al = *(const short8*)(XL + pos * 40 + q * 8);
          #pragma unroll
          for (int nt = 0; nt < 4; ++nt) {
            acc[b][mt][nt] = __builtin_amdgcn_mfma_f32_16x16x32_bf16(ah, bh[nt], acc[b][mt][nt], 0, 0, 0);
            acc[b][mt][nt] = __builtin_amdgcn_mfma_f32_16x16x32_bf16(al, bh[nt], acc[b][mt][nt], 0, 0, 0);
            acc[b][mt][nt] = __builtin_amdgcn_mfma_f32_16x16x32_bf16(ah, bl[nt], acc[b][mt][nt], 0, 0, 0);
          }
        }
      }
    }
  }

  // --- epilogue per batch: acc -> V (BN1+ReLU) -> fp32 1x1 + BN2 + filter ---
  #pragma unroll
  for (int b = 0; b < 2; ++b) {
    __syncthreads();   // staging (b=0) or previous V reads (b=1) complete
    #pragma unroll
    for (int mt = 0; mt < 4; ++mt) {
      #pragma unroll
      for (int nt = 0; nt < 4; ++nt) {
        int co = nt * 16 + lm;
        float A = A1s[co], Cc = C1s[co];
        #pragma unroll
        for (int r = 0; r < 4; ++r) {
          int p = mt * 16 + q * 4 + r;               // pixel within phase (8x8)
          int ur = 2 * (p >> 3) + pr, uc = 2 * (p & 7) + pc;
          V[(ur * 16 + uc) * 65 + co] = fmaxf(fmaf(A, acc[b][mt][nt][r], Cc), 0.f);
        }
      }
    }
    __syncthreads();
    {
      float a2[8];
      #pragma unroll
      for (int c2 = 0; c2 < 8; ++c2) a2[c2] = 0.f;
      const float* vp = &V[tid * 65];
      for (int co = 0; co < 64; ++co) {
        float xv = vp[co];
        #pragma unroll
        for (int c2 = 0; c2 < 8; ++c2) a2[c2] = fmaf(w2s[c2 * 64 + co], xv, a2[c2]);
      }
      int ur = tid >> 4, uc = tid & 15;
      int batch = bz * 2 + b;
      #pragma unroll
      for (int c2 = 0; c2 < 8; ++c2) {
        float y = fmaf(s2s[c2], a2[c2], sh2s[c2]);
        float o = (y > 1.0f) ? y : 0.f;
        xf[((batch * 8 + c2) * 256 + by * 16 + ur) * 256 + bx * 16 + uc] = o;
      }
    }
  }
}

// ---------------------------------------------------------------------------
// K2: exact fixup of the 4 global border lines (R/C in {0,255}) using the
// 12 boundary filter sets. Grid (seg16, line4, bz8); wave=4px, lane=co.
// ---------------------------------------------------------------------------
__global__ __launch_bounds__(256) void k_fix(
    const float* __restrict__ x, const float* __restrict__ EdgeEff,
    const float* __restrict__ b1, const float* __restrict__ g1,
    const float* __restrict__ be1, const float* __restrict__ m1,
    const float* __restrict__ v1, const float* __restrict__ w2,
    const float* __restrict__ g2, const float* __restrict__ be2,
    const float* __restrict__ m2, const float* __restrict__ v2,
    float* __restrict__ xf)
{
  __shared__ float w2s[512];
  __shared__ float A1s[64], C1s[64];
  __shared__ float s2s[8], sh2s[8];
  const int tid = threadIdx.x;
  for (int i = tid; i < 512; i += 256) w2s[i] = w2[i];
  if (tid < 64) {
    float sc = g1[tid] * rsqrtf(v1[tid] + EPS);
    A1s[tid] = sc;
    C1s[tid] = sc * (b1[tid] - m1[tid]) + be1[tid];
  }
  if (tid < 8) {
    float sc = g2[tid] * rsqrtf(v2[tid] + EPS);
    s2s[tid] = sc;
    sh2s[tid] = be2[tid] - m2[tid] * sc;
  }
  __syncthreads();

  const int w = tid >> 6, co = tid & 63;
  const int seg = blockIdx.x, line = blockIdx.y, bz = blockIdx.z;

  int Rk[4], Ck[4], setk[4], validk[4], offs[4][9];
  #pragma unroll
  for (int k = 0; k < 4; ++k) {
    int u = seg * 16 + w * 4 + k;
    int R, C, rs, cs, rbase, cbase, val = 1;
    if (line == 0)      { R = 0;   C = u; rs = 2; rbase = 0; }
    else if (line == 1) { R = 255; C = u; rs = 3; rbase = 125; }
    else                { C = (line == 2) ? 0 : 255; R = 1 + u; val = (u < 254);
                          rs = R & 1; rbase = (R >> 1) - 1; }
    if (line < 2) { cs = (C == 0) ? 2 : ((C == 255) ? 3 : (C & 1));
                    cbase = (cs == 2) ? 0 : ((cs == 3) ? 125 : (C >> 1) - 1); }
    else          { cs = (line == 2) ? 2 : 3; cbase = (line == 2) ? 0 : 125; }
    Rk[k] = R; Ck[k] = C; setk[k] = (rs << 2) | cs; validk[k] = val;
    #pragma unroll
    for (int tap = 0; tap < 9; ++tap) {
      int rr = min(max(rbase + tap / 3, 0), 127);
      int cc = min(max(cbase + tap % 3, 0), 127);
      offs[k][tap] = rr * 128 + cc;
    }
  }

  float acc[4] = {0.f, 0.f, 0.f, 0.f};
  for (int ci = 0; ci < 64; ++ci) {
    const float* xp = x + (size_t)(bz * 64 + ci) * 16384;
    #pragma unroll
    for (int k = 0; k < 4; ++k) {
      const float* ep = EdgeEff + setk[k] * 36864 + ci * 576 + co;
      #pragma unroll
      for (int tap = 0; tap < 9; ++tap)
        acc[k] = fmaf(ep[tap * 64], xp[offs[k][tap]], acc[k]);
    }
  }

  #pragma unroll
  for (int k = 0; k < 4; ++k) {
    float v = fmaxf(fmaf(A1s[co], acc[k], C1s[co]), 0.f);
    float part[8];
    #pragma unroll
    for (int c2 = 0; c2 < 8; ++c2) part[c2] = w2s[c2 * 64 + co] * v;
    #pragma unroll
    for (int m = 1; m < 64; m <<= 1) {
      #pragma unroll
      for (int c2 = 0; c2 < 8; ++c2) part[c2] += __shfl_xor(part[c2], m, 64);
    }
    if (co < 8 && validk[k]) {
      float y = fmaf(s2s[co], part[co], sh2s[co]);
      float o = (y > 1.0f) ? y : 0.f;
      xf[((bz * 8 + co) * 256 + Rk[k]) * 256 + Ck[k]] = o;
    }
  }
}

// ---------------------------------------------------------------------------
// K3: fused separable 5x5 window-sum + row-max; 16-row chunks.
// ---------------------------------------------------------------------------
__global__ __launch_bounds__(256) void k_sep(const float* __restrict__ xf,
                                             float* __restrict__ ws,
                                             float* __restrict__ rm) {
  __shared__ float bufx[20 * 256];
  __shared__ float bufr[20 * 256];
  const int plane = blockIdx.x >> 4;
  const int r0 = (blockIdx.x & 15) * 16;
  const int t = threadIdx.x;
  const float* xp = xf + plane * 65536;

  for (int i = t; i < 20 * 256; i += 256) {
    int rr = r0 - 2 + (i >> 8);
    bufx[i] = ((unsigned)rr < 256u) ? xp[(rr << 8) | (i & 255)] : 0.f;
  }
  __syncthreads();

  #pragma unroll 4
  for (int i = 0; i < 20; ++i) {
    const float* row = bufx + i * 256;
    float s = 0.f;
    #pragma unroll
    for (int d = -2; d <= 2; ++d) {
      int cc = t + d;
      if ((unsigned)cc < 256u) s += row[cc];
    }
    bufr[i * 256 + t] = s;
  }
  __syncthreads();

  #pragma unroll 4
  for (int i = 0; i < 16; ++i) {
    int j = i + 2;
    float s = bufr[(j - 2) * 256 + t] + bufr[(j - 1) * 256 + t] + bufr[j * 256 + t] +
              bufr[(j + 1) * 256 + t] + bufr[(j + 2) * 256 + t];
    bufx[j * 256 + t] = s;
    ws[plane * 65536 + (r0 + i) * 256 + t] = s;
  }
  __syncthreads();

  #pragma unroll 4
  for (int i = 0; i < 16; ++i) {
    int j = i + 2;
    float m = -HUGE_VALF;
    #pragma unroll
    for (int d = -2; d <= 2; ++d) {
      int cc = t + d;
      if ((unsigned)cc < 256u) m = fmaxf(m, bufx[j * 256 + cc]);
    }
    rm[plane * 65536 + (r0 + i) * 256 + t] = m;
  }
}

// ---------------------------------------------------------------------------
// K4: per-(plane, 32-row chunk) NMS mask + stable top-8 candidates.
// ---------------------------------------------------------------------------
__global__ __launch_bounds__(256) void k_cand(const float* __restrict__ ws,
                                              const float* __restrict__ rm,
                                              float* __restrict__ candv,
                                              int* __restrict__ candi) {
  __shared__ float cv[256 * 8];
  __shared__ int cidx[256 * 8];
  const int t = threadIdx.x;
  const int plane = blockIdx.x >> 3;
  const int r0 = (blockIdx.x & 7) * 32;
  const float* wsp = ws + plane * 65536;
  const float* rmp = rm + plane * 65536;

  float bv[8]; int bi[8];
  #pragma unroll
  for (int k = 0; k < 8; ++k) { bv[k] = -HUGE_VALF; bi[k] = 0x7fffffff; }

  float w0 = (r0 >= 2) ? rmp[(r0 - 2) * 256 + t] : -HUGE_VALF;
  float w1v = (r0 >= 1) ? rmp[(r0 - 1) * 256 + t] : -HUGE_VALF;
  float w2v = rmp[r0 * 256 + t];
  float w3v = rmp[(r0 + 1) * 256 + t];
  for (int r = r0; r < r0 + 32; ++r) {
    float w4v = (r + 2 < 256) ? rmp[(r + 2) * 256 + t] : -HUGE_VALF;
    float mp = fmaxf(fmaxf(fmaxf(w0, w1v), fmaxf(w2v, w3v)), w4v);
    float wsv = wsp[r * 256 + t];
    float mv = (wsv == mp) ? wsv : 0.f;
    int e = (r << 8) | t;
    if (better(mv, e, bv[7], bi[7])) {
      bv[7] = mv; bi[7] = e;
      #pragma unroll
      for (int k = 7; k > 0; --k) {
        if (better(bv[k], bi[k], bv[k - 1], bi[k - 1])) {
          float tv = bv[k]; bv[k] = bv[k - 1]; bv[k - 1] = tv;
          int ti = bi[k]; bi[k] = bi[k - 1]; bi[k - 1] = ti;
        }
      }
    }
    w0 = w1v; w1v = w2v; w2v = w3v; w3v = w4v;
  }

  #pragma unroll
  for (int k = 0; k < 8; ++k) { cv[t * 8 + k] = bv[k]; cidx[t * 8 + k] = bi[k]; }
  __syncthreads();

  for (int s = 128; s >= 1; s >>= 1) {
    if (t < s) {
      float ov[8]; int oi[8];
      int ia = 0, ib = 0;
      #pragma unroll
      for (int k = 0; k < 8; ++k) {
        float va = cv[t * 8 + ia];       int xa = cidx[t * 8 + ia];
        float vb = cv[(t + s) * 8 + ib]; int xb = cidx[(t + s) * 8 + ib];
        if (better(va, xa, vb, xb)) { ov[k] = va; oi[k] = xa; ++ia; }
        else                        { ov[k] = vb; oi[k] = xb; ++ib; }
      }
      #pragma unroll
      for (int k = 0; k < 8; ++k) { cv[t * 8 + k] = ov[k]; cidx[t * 8 + k] = oi[k]; }
    }
    __syncthreads();
  }

  if (t < 8) {
    candv[blockIdx.x * 8 + t] = cv[t];
    candi[blockIdx.x * 8 + t] = cidx[t];
  }
}

// ---------------------------------------------------------------------------
// K5: merge 8x8 candidates per plane (rank by total order), extract patches
// and positions.
// ---------------------------------------------------------------------------
__global__ __launch_bounds__(256) void k_final(const float* __restrict__ candv,
                                               const int* __restrict__ candi,
                                               const float* __restrict__ xf,
                                               float* __restrict__ patches,
                                               float* __restrict__ pos) {
  __shared__ float cvs[64];
  __shared__ int cis[64];
  __shared__ int fidx[8];
  const int t = threadIdx.x;
  const int plane = blockIdx.x;

  if (t < 64) { cvs[t] = candv[plane * 64 + t]; cis[t] = candi[plane * 64 + t]; }
  __syncthreads();
  if (t < 64) {
    float v = cvs[t]; int i = cis[t];
    int rank = 0;
    for (int m = 0; m < 64; ++m)
      if (better(cvs[m], cis[m], v, i)) ++rank;
    if (rank < 8) fidx[rank] = i;
  }
  __syncthreads();

  const float* xfp = xf + plane * 65536;
  if (t < 200) {
    int n = t / 25, e = t % 25;
    int kr = e / 5, kc = e % 5;
    int idx = fidx[n];
    int h = idx >> 8, w = idx & 255;
    int rr = h - 2 + kr, cc = w - 2 + kc;
    float v = ((unsigned)rr < 256u && (unsigned)cc < 256u) ? xfp[rr * 256 + cc] : 0.f;
    patches[plane * 200 + t] = v;
  } else if (t < 232) {
    int qq = t - 200;
    int n = qq >> 2, k = qq & 3;
    int idx = fidx[n];
    int h = idx >> 8, w = idx & 255;
    int val;
    if (k == 0)      val = min(max(w - 2, 0), 255);
    else if (k == 1) val = min(max(h - 2, 0), 255);
    else if (k == 2) val = min(max(w + 2, 0), 255);
    else             val = min(max(h + 2, 0), 255);
    pos[plane * 32 + qq] = (float)val;
  }
}

// ---------------------------------------------------------------------------
extern "C" void kernel_launch(void* const* d_in, const int* in_sizes, int n_in,
                              void* d_out, int out_size, void* d_ws, size_t ws_size,
                              hipStream_t stream) {
  (void)in_sizes; (void)n_in; (void)out_size; (void)ws_size;
  const float* x   = (const float*)d_in[0];
  const float* w1  = (const float*)d_in[1];
  const float* b1  = (const float*)d_in[2];
  const float* g1  = (const float*)d_in[3];
  const float* be1 = (const float*)d_in[4];
  const float* m1  = (const float*)d_in[5];
  const float* v1  = (const float*)d_in[6];
  const float* w2  = (const float*)d_in[7];
  const float* g2  = (const float*)d_in[8];
  const float* be2 = (const float*)d_in[9];
  const float* m2  = (const float*)d_in[10];
  const float* v2  = (const float*)d_in[11];

  float* out = (float*)d_out;
  const int PLANE = 8 * 8 * 256 * 256;   // 4,194,304
  float* xf   = (float*)d_ws;
  float* bufA = xf + PLANE;              // rm; prep tables live here pre-k_sep
  float* bufB = bufA + PLANE;            // window sums
  float* candv = bufB + PLANE;           // 4096 floats
  int*   candi = (int*)(candv + 4096);   // 4096 ints
  unsigned short* Wphase = (unsigned short*)bufA;   // 576 KB
  float* EdgeEff = bufA + 147456;                   // 2.25 MB

  k_wprep<<<2880, 256, 0, stream>>>(w1, Wphase, EdgeEff);
  k_front<<<dim3(16, 16, 4), 256, 0, stream>>>(x, Wphase, b1, g1, be1, m1, v1,
                                               w2, g2, be2, m2, v2, xf);
  k_fix<<<dim3(16, 4, 8), 256, 0, stream>>>(x, EdgeEff, b1, g1, be1, m1, v1,
                                            w2, g2, be2, m2, v2, xf);
  k_sep<<<1024, 256, 0, stream>>>(xf, bufB, bufA);
  k_cand<<<512, 256, 0, stream>>>(bufB, bufA, candv, candi);
  k_final<<<64, 256, 0, stream>>>(candv, candi, xf, out, out + 12800);
}